// Round 4
// baseline (250.965 us; speedup 1.0000x reference)
//
#include <hip/hip_runtime.h>

// Problem constants (from reference setup_inputs)
#define BB 2
#define CC 2
#define DD 160
#define HH 192
#define WW 224
#define DHW (DD * HH * WW)
#define NBLK ((DHW + 255) / 256)   // 26880, divisible by 8

typedef float f2v __attribute__((ext_vector_type(2)));

__device__ __forceinline__ f2v load2u(const float* base, int off) {
    struct __attribute__((packed)) S { f2v v; };
    return ((const S*)(base + off))->v;
}

__global__ __launch_bounds__(256) void affine_sample_kernel(
    const float* __restrict__ src,   // [B,C,D,H,W]
    const float* __restrict__ mat,   // [B,3,4]
    float* __restrict__ out)         // [B,C,D,H,W]
{
    // XCD-aware swizzle: XCD k (round-robin = bx%8) gets a contiguous slab
    int bx = blockIdx.x;
    int bs = (bx & 7) * (NBLK / 8) + (bx >> 3);
    int idx = bs * 256 + threadIdx.x;
    if (idx >= DHW) return;
    int b = blockIdx.y;

    int w = idx % WW;
    int t = idx / WW;
    int h = t % HH;
    int d = t / HH;

    // Compose affine + grid-normalization + unnormalize into pixel-space:
    //   ix = C00*w + C01*h + C02*d + C03   (all coefficients wave-uniform)
    const float* m = mat + b * 12;
    float a00 = m[0], a01 = m[1], a02 = m[2],  a03 = m[3]  * (1.0f / (float)DD);
    float a10 = m[4], a11 = m[5], a12 = m[6],  a13 = m[7]  * (1.0f / (float)HH);
    float a20 = m[8], a21 = m[9], a22 = m[10], a23 = m[11] * (1.0f / (float)WW);

    const float sw = (float)(WW - 1) * 0.5f, sh = (float)(HH - 1) * 0.5f, sd = (float)(DD - 1) * 0.5f;
    const float tw = 2.0f / (float)(WW - 1), th = 2.0f / (float)(HH - 1), td = 2.0f / (float)(DD - 1);
    // gx row maps to x (W axis); scale columns by step sizes, fold constant part
    float C00 = a00 * tw * sw, C01 = a01 * th * sw, C02 = a02 * td * sw;
    float C03 = (-(a00 + a01 + a02) + a03 + 1.0f) * sw;
    float C10 = a10 * tw * sh, C11 = a11 * th * sh, C12 = a12 * td * sh;
    float C13 = (-(a10 + a11 + a12) + a13 + 1.0f) * sh;
    float C20 = a20 * tw * sd, C21 = a21 * th * sd, C22 = a22 * td * sd;
    float C23 = (-(a20 + a21 + a22) + a23 + 1.0f) * sd;

    float fw = (float)w, fh = (float)h, fd = (float)d;
    float ix = fmaf(C00, fw, fmaf(C01, fh, fmaf(C02, fd, C03)));
    float iy = fmaf(C10, fw, fmaf(C11, fh, fmaf(C12, fd, C13)));
    float iz = fmaf(C20, fw, fmaf(C21, fh, fmaf(C22, fd, C23)));

    float fx0 = floorf(ix), fy0 = floorf(iy), fz0 = floorf(iz);
    float fx = ix - fx0, fy = iy - fy0, fz = iz - fz0;
    int x0 = (int)fx0, y0 = (int)fy0, z0 = (int)fz0;
    int x1 = x0 + 1, y1 = y0 + 1, z1 = z0 + 1;

    // 1-D weights with boundary validity folded in
    float wx0 = (x0 >= 0 && x0 < WW) ? (1.0f - fx) : 0.0f;
    float wx1 = (x1 >= 0 && x1 < WW) ? fx          : 0.0f;
    float wy0 = (y0 >= 0 && y0 < HH) ? (1.0f - fy) : 0.0f;
    float wy1 = (y1 >= 0 && y1 < HH) ? fy          : 0.0f;
    float wz0 = (z0 >= 0 && z0 < DD) ? (1.0f - fz) : 0.0f;
    float wz1 = (z1 >= 0 && z1 < DD) ? fz          : 0.0f;

    // clamped indices — always safe to load
    int xc0 = min(max(x0, 0), WW - 1), xc1 = min(max(x1, 0), WW - 1);
    int yc0 = min(max(y0, 0), HH - 1), yc1 = min(max(y1, 0), HH - 1);
    int zc0 = min(max(z0, 0), DD - 1), zc1 = min(max(z1, 0), DD - 1);

    // x-pair base: one 8B load covers both x corners.
    // Fold the clamp-selects into pair weights A (element 0) / B (element 1):
    //   A = wx0*(sel0==0) + wx1*(sel1==0),  B = wx0*sel0 + wx1*sel1
    int xb   = min(xc0, WW - 2);
    int sel0 = xc0 - xb;             // 0 or 1
    int sel1 = xc1 - xb;             // 0 or 1
    float A = wx0 * (float)(1 - sel0) + wx1 * (float)(1 - sel1);
    float B = wx0 * (float)sel0      + wx1 * (float)sel1;

    // wave-uniform channel bases; 32-bit per-lane offsets -> saddr loads
    const float* sbase0 = src + (size_t)b * CC * DHW;
    const float* sbase1 = sbase0 + DHW;

    int o00 = (zc0 * HH + yc0) * WW + xb;
    int o01 = (zc0 * HH + yc1) * WW + xb;
    int o10 = (zc1 * HH + yc0) * WW + xb;
    int o11 = (zc1 * HH + yc1) * WW + xb;

    // 8 gathers, issued back-to-back
    f2v pa00 = load2u(sbase0, o00);
    f2v pa01 = load2u(sbase0, o01);
    f2v pa10 = load2u(sbase0, o10);
    f2v pa11 = load2u(sbase0, o11);
    f2v pb00 = load2u(sbase1, o00);
    f2v pb01 = load2u(sbase1, o01);
    f2v pb10 = load2u(sbase1, o10);
    f2v pb11 = load2u(sbase1, o11);

    float w00 = wz0 * wy0, w01 = wz0 * wy1;
    float w10 = wz1 * wy0, w11 = wz1 * wy1;

    float a00w = w00 * A, b00w = w00 * B;
    float a01w = w01 * A, b01w = w01 * B;
    float a10w = w10 * A, b10w = w10 * B;
    float a11w = w11 * A, b11w = w11 * B;

    float acc0 = fmaf(a00w, pa00[0], fmaf(b00w, pa00[1],
                 fmaf(a01w, pa01[0], fmaf(b01w, pa01[1],
                 fmaf(a10w, pa10[0], fmaf(b10w, pa10[1],
                 fmaf(a11w, pa11[0], b11w * pa11[1])))))));
    float acc1 = fmaf(a00w, pb00[0], fmaf(b00w, pb00[1],
                 fmaf(a01w, pb01[0], fmaf(b01w, pb01[1],
                 fmaf(a10w, pb10[0], fmaf(b10w, pb10[1],
                 fmaf(a11w, pb11[0], b11w * pb11[1])))))));

    float* obase = out + (size_t)b * CC * DHW;
    __builtin_nontemporal_store(acc0, obase + idx);
    __builtin_nontemporal_store(acc1, obase + DHW + idx);
}

extern "C" void kernel_launch(void* const* d_in, const int* in_sizes, int n_in,
                              void* d_out, int out_size, void* d_ws, size_t ws_size,
                              hipStream_t stream) {
    const float* src = (const float*)d_in[0];
    const float* mat = (const float*)d_in[1];
    float* out = (float*)d_out;

    dim3 block(256);
    dim3 grid(NBLK, BB);
    affine_sample_kernel<<<grid, block, 0, stream>>>(src, mat, out);
}